// Round 10
// baseline (248.705 us; speedup 1.0000x reference)
//
#include <hip/hip_runtime.h>
#include <float.h>
#include <stdint.h>

// WindowRouting: out[b][q][0..3] = indices of top-4 of (Q[b,q,:] . I[b,m,:]) over m.
// Scale dropped (order-preserving).
//
// R18 = R17 (proven 129.5us total, wr_mfma 64.3us, VGPR 108) + K-split
// accumulators. R17 ledger: 2410 cy/step-slot = 270 MFMA + 1080 VALU + ~1060
// stall; last untested dependency = the 8-deep serial MFMA accumulate chain
// (dep latency >> 8cy throughput, only 2-way ILP). This round: 4 independent
// chains of depth 4 (c0a ks0-3, c0b ks4-7, c1a, c1b), round-robin issue,
// merged with 16 v_add_f32 per output before selection. fp32 reassociation
// ~1ulp << 11-bit key truncation; fp64 refine exact -> output unchanged.
// Micro: key pack as (bits & 0xFFFFF800)|(kr & 0x7FF) -> LLVM v_bfi_b32.
// Sentinels: VGPR <= ~170, WRITE_SIZE ~256KB, FETCH ~27MB.
// Null outcome (+-2us) -> dep-latency theory dead, finalize R17 next round.
//
// K0 (wr_cvt): fp32 -> bf16, DIRECT (no LDS/sync), 32x32-fragment-linear
//   layouts for image (A) and query (B). (R17, passed)
// K1 (wr_mfma): 256 blocks x 512 thr. Block = 64 q x all 8192 m; wave =
//   m-eighth (32 tiles of 32 m). Per step: 16x mfma_f32_32x32x16_bf16,
//   8x 16B loads (2-deep ring), 32 key-inserts. A row=lane&31,
//   k=ks*16+(lane>>5)*8; C/D row=(reg&3)+8*(reg>>2)+4*(lane>>5), col=lane&31
//   (HW-verified m74/m101). Keys: low 11 bits = 2047 - m_local. Epilogue:
//   rank-select top-8 of 32 -> fp64 refine -> exact top-4. (R11/R17, passed)
// Fallback: fp32 LDS-tiled kernel if ws too small (unchanged).

#define NBATCH 4
#define NQ 4096
#define NM 8192
#define KD 128

typedef unsigned short ushort_t;
typedef __attribute__((ext_vector_type(8))) short bf16x8;
typedef __attribute__((ext_vector_type(4))) float f32x4;
typedef __attribute__((ext_vector_type(16))) float f32x16;

#define BETTER64(v, i, w, j) (((v) > (w)) || ((v) == (w) && (i) < (j)))

__device__ inline float fmed3(float a, float b, float c) {
#if __has_builtin(__builtin_amdgcn_fmed3f)
  return __builtin_amdgcn_fmed3f(a, b, c);
#else
  return fmaxf(fminf(a, b), fminf(fmaxf(a, b), c));
#endif
}

__device__ inline ushort_t f2bf(float f) {
  unsigned u = __float_as_uint(f);
  u += 0x7fffu + ((u >> 16) & 1u);  // RNE
  return (ushort_t)(u >> 16);
}

__device__ inline unsigned pk2(float a, float b) {
  return (unsigned)f2bf(a) | ((unsigned)f2bf(b) << 16);
}

// ---------------- K0: direct convert + swizzle (no LDS) ----------------
// Image ib (per batch 131072 int4): idx = e*16384 + tile*512 + ks*64 + l
//   -> m = e*1024 + tile*32 + (l&31), k = ks*16 + (l>>5)*8, 8 bf16 elems.
// Query qb (per batch 65536 int4): idx = qt*1024 + h*512 + ks*64 + l
//   -> q = qt*64 + h*32 + (l&31), k = ks*16 + (l>>5)*8, 8 bf16 elems.
__global__ __launch_bounds__(256) void wr_cvt(const float* __restrict__ qry,
                                              const float* __restrict__ img,
                                              int4* __restrict__ qb,
                                              int4* __restrict__ ib) {
  const int t = (int)blockIdx.x * 256 + (int)threadIdx.x;  // 0..786431
  if (t < 524288) {
    // image: one ib int4 per thread
    const int b = t >> 17;
    const int tt = t & 131071;
    const int e = tt >> 14;
    const int r = tt & 16383;
    const int tile = r >> 9;
    const int ks = (r >> 6) & 7;
    const int l = r & 63;
    const int m = e * 1024 + tile * 32 + (l & 31);
    const int k0 = ks * 16 + (l >> 5) * 8;
    const float* src = img + ((size_t)(b * NM + m)) * KD + k0;
    const float4 v0 = *(const float4*)(src);
    const float4 v1 = *(const float4*)(src + 4);
    int4 o;
    o.x = (int)pk2(v0.x, v0.y);
    o.y = (int)pk2(v0.z, v0.w);
    o.z = (int)pk2(v1.x, v1.y);
    o.w = (int)pk2(v1.z, v1.w);
    ib[t] = o;
  } else {
    // query: one qb int4 per thread
    const int u = t - 524288;  // 0..262143
    const int b = u >> 16;
    const int uu = u & 65535;
    const int qt = uu >> 10;
    const int r = uu & 1023;
    const int h = r >> 9;
    const int ks = (r >> 6) & 7;
    const int l = r & 63;
    const int q = qt * 64 + h * 32 + (l & 31);
    const int k0 = ks * 16 + (l >> 5) * 8;
    const float* src = qry + ((size_t)(b * NQ + q)) * KD + k0;
    const float4 v0 = *(const float4*)(src);
    const float4 v1 = *(const float4*)(src + 4);
    int4 o;
    o.x = (int)pk2(v0.x, v0.y);
    o.y = (int)pk2(v0.z, v0.w);
    o.z = (int)pk2(v1.x, v1.y);
    o.w = (int)pk2(v1.z, v1.w);
    qb[u] = o;
  }
}

// ---------------- K1: 32x32 MFMA screen (K-split ILP) + fp64 refine ----------------
__global__ __launch_bounds__(512, 1) void wr_mfma(const float* __restrict__ qry,
                                                  const float* __restrict__ img,
                                                  const int4* __restrict__ qb,
                                                  const int4* __restrict__ ib,
                                                  int* __restrict__ out) {
  const int bid = (int)blockIdx.x;               // 0..255
  const int b = (bid & 7) >> 1;                  // batch pinned to XCD pair
  const int qt = ((bid >> 3) << 1) | (bid & 1);  // 0..63
  const int qbase = qt * 64;

  const int tid = (int)threadIdx.x;
  const int lane = tid & 63;
  const int w = tid >> 6;        // 0..7 -> m-eighth (32 tiles of 32 m)
  const int l31 = lane & 31;
  const int lh = lane >> 5;      // 0..1

  const int4* Qb = qb + (size_t)b * 65536 + qt * 1024;
  const int4* ibc = ib + (size_t)b * 131072 + w * 16384;

  // query fragments pinned: 2 q-halves x 8 k-slices. B[k=ks*16+lh*8+j][q=l31]
  bf16x8 bfrag[2][8];  // 64 VGPRs
#pragma unroll
  for (int h = 0; h < 2; ++h)
#pragma unroll
    for (int ks = 0; ks < 8; ++ks)
      bfrag[h][ks] = *(const bf16x8*)&Qb[h * 512 + ks * 64 + lane];

  float tch[2][4];  // one packed-key top-4 chain per q-half
#pragma unroll
  for (int c = 0; c < 2; ++c)
#pragma unroll
    for (int e = 0; e < 4; ++e) tch[c][e] = -FLT_MAX;

  bf16x8 A0[8], A1[8];  // 2-deep ring, 32 VGPRs each

  auto loadA = [&](bf16x8* A, int t) {
    const int4* p = ibc + t * 512 + lane;
#pragma unroll
    for (int ks = 0; ks < 8; ++ks) A[ks] = *(const bf16x8*)&p[ks * 64];
  };

  const f32x16 z16 = {0.f, 0.f, 0.f, 0.f, 0.f, 0.f, 0.f, 0.f,
                      0.f, 0.f, 0.f, 0.f, 0.f, 0.f, 0.f, 0.f};

  int hl = 2;
  int vbase = 2047 - 4 * lh;  // kr = vbase - row; m_local = tile*32+row+4*lh

  auto step = [&](bf16x8* A) {
    // 4 independent accumulator chains of depth 4 (K-split: ks 0-3 | 4-7),
    // round-robin issue. All 16 MFMAs consume A before the refill below.
    f32x16 c0a = __builtin_amdgcn_mfma_f32_32x32x16_bf16(A[0], bfrag[0][0], z16,
                                                         0, 0, 0);
    f32x16 c1a = __builtin_amdgcn_mfma_f32_32x32x16_bf16(A[0], bfrag[1][0], z16,
                                                         0, 0, 0);
    f32x16 c0b = __builtin_amdgcn_mfma_f32_32x32x16_bf16(A[4], bfrag[0][4], z16,
                                                         0, 0, 0);
    f32x16 c1b = __builtin_amdgcn_mfma_f32_32x32x16_bf16(A[4], bfrag[1][4], z16,
                                                         0, 0, 0);
#pragma unroll
    for (int ks = 1; ks < 4; ++ks) {
      c0a = __builtin_amdgcn_mfma_f32_32x32x16_bf16(A[ks], bfrag[0][ks], c0a,
                                                    0, 0, 0);
      c1a = __builtin_amdgcn_mfma_f32_32x32x16_bf16(A[ks], bfrag[1][ks], c1a,
                                                    0, 0, 0);
      c0b = __builtin_amdgcn_mfma_f32_32x32x16_bf16(A[ks + 4], bfrag[0][ks + 4],
                                                    c0b, 0, 0, 0);
      c1b = __builtin_amdgcn_mfma_f32_32x32x16_bf16(A[ks + 4], bfrag[1][ks + 4],
                                                    c1b, 0, 0, 0);
    }
    if (hl < 32) loadA(A, hl);  // refill for use 2 steps later
    ++hl;
#pragma unroll
    for (int rg = 0; rg < 16; ++rg) {
      const unsigned kr =
          (unsigned)(vbase - ((rg & 3) + 8 * (rg >> 2))) & 0x7FFu;
      const float s0 = c0a[rg] + c0b[rg];
      const float s1 = c1a[rg] + c1b[rg];
      // disjoint-mask or -> v_bfi_b32
      float k = __uint_as_float((__float_as_uint(s0) & 0xFFFFF800u) | kr);
      tch[0][3] = fmed3(k, tch[0][2], tch[0][3]);
      tch[0][2] = fmed3(k, tch[0][1], tch[0][2]);
      tch[0][1] = fmed3(k, tch[0][0], tch[0][1]);
      tch[0][0] = fmaxf(tch[0][0], k);
      k = __uint_as_float((__float_as_uint(s1) & 0xFFFFF800u) | kr);
      tch[1][3] = fmed3(k, tch[1][2], tch[1][3]);
      tch[1][2] = fmed3(k, tch[1][1], tch[1][2]);
      tch[1][1] = fmed3(k, tch[1][0], tch[1][1]);
      tch[1][0] = fmaxf(tch[1][0], k);
    }
    vbase -= 32;
  };

  loadA(A0, 0);
  loadA(A1, 1);
  for (int g = 0; g < 16; ++g) { step(A0); step(A1); }  // tiles 0..31

  // ---- merge across lane-halves (rows complementary), snapshot-first ----
#pragma unroll
  for (int c = 0; c < 2; ++c) {
    float k4[4];
#pragma unroll
    for (int e = 0; e < 4; ++e) k4[e] = __shfl_xor(tch[c][e], 32, 64);
#pragma unroll
    for (int e = 0; e < 4; ++e) {
      const float k = k4[e];
      tch[c][3] = fmed3(k, tch[c][2], tch[c][3]);
      tch[c][2] = fmed3(k, tch[c][1], tch[c][2]);
      tch[c][1] = fmed3(k, tch[c][0], tch[c][1]);
      tch[c][0] = fmaxf(tch[c][0], k);
    }
  }

  // ---- 32 candidates per q-row (8 eighths x 4), 64 rows ----
  __shared__ float ck[64][33];
  __shared__ int top8[64][8];
  __shared__ double pd[64][8];
  __shared__ int pi[64][8];

  if (lane < 32) {
#pragma unroll
    for (int c = 0; c < 2; ++c)
#pragma unroll
      for (int e = 0; e < 4; ++e) ck[c * 32 + l31][w * 4 + e] = tch[c][e];
  }
  __syncthreads();

  // ---- rank-select top-8 of 32 packed keys per row (ranks unique) ----
  for (int p = tid; p < 2048; p += 512) {
    const int q = p >> 5;
    const int j = p & 31;
    const float k = ck[q][j];
    int rank = 0;
#pragma unroll 8
    for (int i = 0; i < 32; ++i) {
      const float o = ck[q][i];
      rank += (o > k) || (o == k && i < j);
    }
    if (rank < 8) {
      const unsigned bits = __float_as_uint(k);
      top8[q][rank] = (j >> 2) * 1024 + 2047 - (int)(bits & 0x7FFu);
    }
  }
  __syncthreads();

  // ---- fp64 refine: one candidate per thread (64 rows x 8) ----
  {
    const int q = tid >> 3;
    const int slot = tid & 7;
    const int m = top8[q][slot];
    const float* qrow = qry + ((size_t)b * NQ + qbase + q) * KD;
    const float* irow = img + ((size_t)b * NM + m) * KD;
    double s0 = 0.0, s1 = 0.0, s2 = 0.0, s3 = 0.0;
#pragma unroll
    for (int k = 0; k < KD; k += 4) {
      const float4 xv = *(const float4*)(qrow + k);
      const float4 yv = *(const float4*)(irow + k);
      s0 = fma((double)xv.x, (double)yv.x, s0);
      s1 = fma((double)xv.y, (double)yv.y, s1);
      s2 = fma((double)xv.z, (double)yv.z, s2);
      s3 = fma((double)xv.w, (double)yv.w, s3);
    }
    pd[q][slot] = (s0 + s1) + (s2 + s3);
    pi[q][slot] = m;
  }
  __syncthreads();

  // ---- exact top-4 of 8 refined, (value desc, index asc) ----
  if (tid < 64) {
    const int q = tid;
    double fv[4];
    int fi[4];
#pragma unroll
    for (int e = 0; e < 4; ++e) { fv[e] = -DBL_MAX; fi[e] = 0x7fffffff; }
    for (int sl = 0; sl < 8; ++sl) {
      const double v = pd[q][sl];
      const int m = pi[q][sl];
      const bool b0 = BETTER64(v, m, fv[0], fi[0]);
      const bool b1 = BETTER64(v, m, fv[1], fi[1]);
      const bool b2 = BETTER64(v, m, fv[2], fi[2]);
      const bool b3 = BETTER64(v, m, fv[3], fi[3]);
      fv[3] = b2 ? fv[2] : (b3 ? v : fv[3]);
      fi[3] = b2 ? fi[2] : (b3 ? m : fi[3]);
      fv[2] = b1 ? fv[1] : (b2 ? v : fv[2]);
      fi[2] = b1 ? fi[1] : (b2 ? m : fi[2]);
      fv[1] = b0 ? fv[0] : (b1 ? v : fv[1]);
      fi[1] = b0 ? fi[0] : (b1 ? m : fi[1]);
      fv[0] = b0 ? v : fv[0];
      fi[0] = b0 ? m : fi[0];
    }
    int4 o;
    o.x = fi[0]; o.y = fi[1]; o.z = fi[2]; o.w = fi[3];
    *(int4*)(out + ((size_t)b * NQ + qbase + q) * 4) = o;
  }
}

// ---------------- Fallback: fp32 LDS-tiled kernel (ws too small) ----------------
#define QT 64
#define MT 128
#define KC 64
#define NTHREADS 512

__global__ __launch_bounds__(NTHREADS) void wr_main(const float* __restrict__ qry,
                                                    const float* __restrict__ img,
                                                    int* __restrict__ out) {
  __shared__ __align__(16) float A_lds[KD * QT];
  __shared__ __align__(16) float B_lds[KC * MT];

  const int t = (int)threadIdx.x;
  const int b = (int)blockIdx.x >> 6;
  const int qbase = ((int)blockIdx.x & 63) * QT;

  const float* qp = qry + ((size_t)b * NQ + qbase) * KD;
  const float* ip = img + (size_t)b * NM * KD;

  {
    const int r = t >> 3;
    const int kc = t & 7;
    const float* src = qp + (size_t)r * KD;
#pragma unroll
    for (int i = 0; i < 4; ++i) {
      const int k0 = kc * 4 + i * 32;
      const float4 v = *(const float4*)(src + k0);
      A_lds[(k0 + 0) * QT + r] = v.x;
      A_lds[(k0 + 1) * QT + r] = v.y;
      A_lds[(k0 + 2) * QT + r] = v.z;
      A_lds[(k0 + 3) * QT + r] = v.w;
    }
  }

  const int qi = t >> 5;
  const int mi = t & 31;

  float tv[4][4];
  int ti[4][4];
#pragma unroll
  for (int j = 0; j < 4; ++j)
#pragma unroll
    for (int s = 0; s < 4; ++s) { tv[j][s] = -FLT_MAX; ti[j][s] = 0x7fffffff; }

  for (int tile = 0; tile < NM / MT; ++tile) {
    const int mbase = tile * MT;
    float acc[4][4];
#pragma unroll
    for (int j = 0; j < 4; ++j)
#pragma unroll
      for (int s = 0; s < 4; ++s) acc[j][s] = 0.0f;

    for (int kb = 0; kb < KD; kb += KC) {
      __syncthreads();
      {
        const int r = t >> 2;
        const int kc = t & 3;
        const float* src = ip + (size_t)(mbase + r) * KD + kb;
#pragma unroll
        for (int i = 0; i < 4; ++i) {
          const int k0 = kc * 4 + i * 16;
          const float4 v = *(const float4*)(src + k0);
          B_lds[(k0 + 0) * MT + r] = v.x;
          B_lds[(k0 + 1) * MT + r] = v.y;
          B_lds[(k0 + 2) * MT + r] = v.z;
          B_lds[(k0 + 3) * MT + r] = v.w;
        }
      }
      __syncthreads();

#pragma unroll 8
      for (int k = 0; k < KC; ++k) {
        const float4 av = *(const float4*)&A_lds[(kb + k) * QT + qi * 4];
        const float4 bv = *(const float4*)&B_lds[k * MT + mi * 4];
        acc[0][0] = fmaf(av.x, bv.x, acc[0][0]);
        acc[0][1] = fmaf(av.x, bv.y, acc[0][1]);
        acc[0][2] = fmaf(av.x, bv.z, acc[0][2]);
        acc[0][3] = fmaf(av.x, bv.w, acc[0][3]);
        acc[1][0] = fmaf(av.y, bv.x, acc[1][0]);
        acc[1][1] = fmaf(av.y, bv.y, acc[1][1]);
        acc[1][2] = fmaf(av.y, bv.z, acc[1][2]);
        acc[1][3] = fmaf(av.y, bv.w, acc[1][3]);
        acc[2][0] = fmaf(av.z, bv.x, acc[2][0]);
        acc[2][1] = fmaf(av.z, bv.y, acc[2][1]);
        acc[2][2] = fmaf(av.z, bv.z, acc[2][2]);
        acc[2][3] = fmaf(av.z, bv.w, acc[2][3]);
        acc[3][0] = fmaf(av.w, bv.x, acc[3][0]);
        acc[3][1] = fmaf(av.w, bv.y, acc[3][1]);
        acc[3][2] = fmaf(av.w, bv.z, acc[3][2]);
        acc[3][3] = fmaf(av.w, bv.w, acc[3][3]);
      }
    }

#pragma unroll
    for (int j = 0; j < 4; ++j) {
#pragma unroll
      for (int s = 0; s < 4; ++s) {
        const float v = acc[j][s];
        const int m = mbase + mi * 4 + s;
        const bool b0 = v > tv[j][0];
        const bool b1 = v > tv[j][1];
        const bool b2 = v > tv[j][2];
        const bool b3 = v > tv[j][3];
        tv[j][3] = b2 ? tv[j][2] : (b3 ? v : tv[j][3]);
        ti[j][3] = b2 ? ti[j][2] : (b3 ? m : ti[j][3]);
        tv[j][2] = b1 ? tv[j][1] : (b2 ? v : tv[j][2]);
        ti[j][2] = b1 ? ti[j][1] : (b2 ? m : ti[j][2]);
        tv[j][1] = b0 ? tv[j][0] : (b1 ? v : tv[j][1]);
        ti[j][1] = b0 ? ti[j][0] : (b1 ? m : ti[j][1]);
        tv[j][0] = b0 ? v : tv[j][0];
        ti[j][0] = b0 ? m : ti[j][0];
      }
    }
  }

  __syncthreads();
  int* idx_lds = (int*)B_lds;
#pragma unroll
  for (int j = 0; j < 4; ++j)
#pragma unroll
    for (int s = 0; s < 4; ++s)
      idx_lds[(qi * 4 + j) * 128 + mi * 4 + s] = ti[j][s];
  __syncthreads();

  double* pv = (double*)A_lds;
  int* piL = (int*)(A_lds + 4096);
  {
    const int r = t >> 3;
    const int slot = t & 7;
    const float* qrow = qp + (size_t)r * KD;
    double bv[4];
    int bi[4];
#pragma unroll
    for (int e = 0; e < 4; ++e) { bv[e] = -DBL_MAX; bi[e] = 0x7fffffff; }

    for (int c = 0; c < 16; ++c) {
      const int m = idx_lds[r * 128 + slot * 16 + c];
      const float* irow = ip + (size_t)m * KD;
      double s0 = 0.0, s1 = 0.0, s2 = 0.0, s3 = 0.0;
#pragma unroll
      for (int k = 0; k < KD; k += 4) {
        const float4 xv = *(const float4*)(qrow + k);
        const float4 yv = *(const float4*)(irow + k);
        s0 = fma((double)xv.x, (double)yv.x, s0);
        s1 = fma((double)xv.y, (double)yv.y, s1);
        s2 = fma((double)xv.z, (double)yv.z, s2);
        s3 = fma((double)xv.w, (double)yv.w, s3);
      }
      const double v = (s0 + s1) + (s2 + s3);
      const bool b0 = BETTER64(v, m, bv[0], bi[0]);
      const bool b1 = BETTER64(v, m, bv[1], bi[1]);
      const bool b2 = BETTER64(v, m, bv[2], bi[2]);
      const bool b3 = BETTER64(v, m, bv[3], bi[3]);
      bv[3] = b2 ? bv[2] : (b3 ? v : bv[3]);
      bi[3] = b2 ? bi[2] : (b3 ? m : bi[3]);
      bv[2] = b1 ? bv[1] : (b2 ? v : bv[2]);
      bi[2] = b1 ? bi[1] : (b2 ? m : bi[2]);
      bv[1] = b0 ? bv[0] : (b1 ? v : bv[1]);
      bi[1] = b0 ? bi[0] : (b1 ? m : bi[1]);
      bv[0] = b0 ? v : bv[0];
      bi[0] = b0 ? m : bi[0];
    }
#pragma unroll
    for (int e = 0; e < 4; ++e) {
      pv[t * 4 + e] = bv[e];
      piL[t * 4 + e] = bi[e];
    }
  }
  __syncthreads();

  if (t < QT) {
    double fv[4];
    int fi[4];
#pragma unroll
    for (int e = 0; e < 4; ++e) { fv[e] = -DBL_MAX; fi[e] = 0x7fffffff; }
    for (int sl = 0; sl < 8; ++sl) {
#pragma unroll
      for (int e = 0; e < 4; ++e) {
        const double v = pv[(t * 8 + sl) * 4 + e];
        const int m = piL[(t * 8 + sl) * 4 + e];
        const bool b0 = BETTER64(v, m, fv[0], fi[0]);
        const bool b1 = BETTER64(v, m, fv[1], fi[1]);
        const bool b2 = BETTER64(v, m, fv[2], fi[2]);
        const bool b3 = BETTER64(v, m, fv[3], fi[3]);
        fv[3] = b2 ? fv[2] : (b3 ? v : fv[3]);
        fi[3] = b2 ? fi[2] : (b3 ? m : fi[3]);
        fv[2] = b1 ? fv[1] : (b2 ? v : fv[2]);
        fi[2] = b1 ? fi[1] : (b2 ? m : fi[2]);
        fv[1] = b0 ? fv[0] : (b1 ? v : fv[1]);
        fi[1] = b0 ? fi[0] : (b1 ? m : fi[1]);
        fv[0] = b0 ? v : fv[0];
        fi[0] = b0 ? m : fi[0];
      }
    }
    int4 o;
    o.x = fi[0]; o.y = fi[1]; o.z = fi[2]; o.w = fi[3];
    *(int4*)(out + ((size_t)b * NQ + qbase + t) * 4) = o;
  }
}

extern "C" void kernel_launch(void* const* d_in, const int* in_sizes, int n_in,
                              void* d_out, int out_size, void* d_ws, size_t ws_size,
                              hipStream_t stream) {
  const float* qry = (const float*)d_in[0];  // (4, 4096, 128) fp32
  const float* img = (const float*)d_in[1];  // (4, 8192, 128) fp32
  int* out = (int*)d_out;                    // (4, 4096, 4) int32

  const size_t qbBytes = (size_t)NBATCH * NQ * KD * sizeof(ushort_t);  // 4 MB
  const size_t ibBytes = (size_t)NBATCH * NM * KD * sizeof(ushort_t);  // 8 MB

  if (ws_size >= qbBytes + ibBytes) {
    int4* qb = (int4*)d_ws;
    int4* ib = (int4*)((char*)d_ws + qbBytes);
    wr_cvt<<<3072, 256, 0, stream>>>(qry, img, qb, ib);
    wr_mfma<<<256, 512, 0, stream>>>(qry, img, qb, ib, out);
  } else {
    wr_main<<<NBATCH * (NQ / QT), NTHREADS, 0, stream>>>(qry, img, out);
  }
}

// Round 11
// 130.776 us; speedup vs baseline: 1.9018x; 1.9018x over previous
//
#include <hip/hip_runtime.h>
#include <float.h>
#include <stdint.h>

// WindowRouting: out[b][q][0..3] = indices of top-4 of (Q[b,q,:] . I[b,m,:]) over m.
// Scale dropped (order-preserving).
//
// R19 = R17 VERBATIM (session best: 129.5us total, wr_mfma 64.3us, VGPR 108,
// WRITE 256KB, FETCH 27MB, absmax 0.0). R18's K-split ILP experiment hit the
// register-allocator heuristic cliff (capped 128, 28MB scratch, 184us) and is
// reverted. Session evidence for why R17 is the stopping point:
//  - fixed ~57us per-graph harness overhead (R14: identical for 1 vs 2
//    dispatches) bounds the achievable total;
//  - the remaining ~40us screen-loop stall is invariant under 2->3.2
//    waves/SIMD (R13), worse with 3x fewer select ops (R15), unchanged with
//    select dependency broken (R16), improved only by halving step count
//    (R17: 32x32 MFMA, -8%);
//  - further ILP (R18) and fusion (R14) both regress on compiler/overhead
//    cliffs.
//
// K0 (wr_cvt): fp32 -> bf16, DIRECT (no LDS/sync), 32x32-fragment-linear
//   layouts for image (A) and query (B).
// K1 (wr_mfma): 256 blocks x 512 thr. Block = 64 q x all 8192 m; wave =
//   m-eighth (32 tiles of 32 m). Per step: 16x mfma_f32_32x32x16_bf16 (2
//   output tiles x 8 K-slices), 8x 16B coalesced loads (2-deep ring), 32
//   key-inserts. A row=lane&31, k=ks*16+(lane>>5)*8; C/D row=(reg&3)+
//   8*(reg>>2)+4*(lane>>5), col=lane&31 (HW-verified m74/m101). Keys: low 11
//   bits = 2047 - m_local, m_local = tile*32+row < 1024. Epilogue: quad-merge
//   across lane-halves -> 32 cand/row -> rank-select top-8 -> fp64 refine ->
//   exact top-4 (value desc, index asc).
// Fallback: fp32 LDS-tiled kernel if ws too small.

#define NBATCH 4
#define NQ 4096
#define NM 8192
#define KD 128

typedef unsigned short ushort_t;
typedef __attribute__((ext_vector_type(8))) short bf16x8;
typedef __attribute__((ext_vector_type(4))) float f32x4;
typedef __attribute__((ext_vector_type(16))) float f32x16;

#define BETTER64(v, i, w, j) (((v) > (w)) || ((v) == (w) && (i) < (j)))

__device__ inline float fmed3(float a, float b, float c) {
#if __has_builtin(__builtin_amdgcn_fmed3f)
  return __builtin_amdgcn_fmed3f(a, b, c);
#else
  return fmaxf(fminf(a, b), fminf(fmaxf(a, b), c));
#endif
}

__device__ inline ushort_t f2bf(float f) {
  unsigned u = __float_as_uint(f);
  u += 0x7fffu + ((u >> 16) & 1u);  // RNE
  return (ushort_t)(u >> 16);
}

__device__ inline unsigned pk2(float a, float b) {
  return (unsigned)f2bf(a) | ((unsigned)f2bf(b) << 16);
}

// ---------------- K0: direct convert + swizzle (no LDS) ----------------
// Image ib (per batch 131072 int4): idx = e*16384 + tile*512 + ks*64 + l
//   -> m = e*1024 + tile*32 + (l&31), k = ks*16 + (l>>5)*8, 8 bf16 elems.
// Query qb (per batch 65536 int4): idx = qt*1024 + h*512 + ks*64 + l
//   -> q = qt*64 + h*32 + (l&31), k = ks*16 + (l>>5)*8, 8 bf16 elems.
__global__ __launch_bounds__(256) void wr_cvt(const float* __restrict__ qry,
                                              const float* __restrict__ img,
                                              int4* __restrict__ qb,
                                              int4* __restrict__ ib) {
  const int t = (int)blockIdx.x * 256 + (int)threadIdx.x;  // 0..786431
  if (t < 524288) {
    // image: one ib int4 per thread
    const int b = t >> 17;
    const int tt = t & 131071;
    const int e = tt >> 14;
    const int r = tt & 16383;
    const int tile = r >> 9;
    const int ks = (r >> 6) & 7;
    const int l = r & 63;
    const int m = e * 1024 + tile * 32 + (l & 31);
    const int k0 = ks * 16 + (l >> 5) * 8;
    const float* src = img + ((size_t)(b * NM + m)) * KD + k0;
    const float4 v0 = *(const float4*)(src);
    const float4 v1 = *(const float4*)(src + 4);
    int4 o;
    o.x = (int)pk2(v0.x, v0.y);
    o.y = (int)pk2(v0.z, v0.w);
    o.z = (int)pk2(v1.x, v1.y);
    o.w = (int)pk2(v1.z, v1.w);
    ib[t] = o;
  } else {
    // query: one qb int4 per thread
    const int u = t - 524288;  // 0..262143
    const int b = u >> 16;
    const int uu = u & 65535;
    const int qt = uu >> 10;
    const int r = uu & 1023;
    const int h = r >> 9;
    const int ks = (r >> 6) & 7;
    const int l = r & 63;
    const int q = qt * 64 + h * 32 + (l & 31);
    const int k0 = ks * 16 + (l >> 5) * 8;
    const float* src = qry + ((size_t)(b * NQ + q)) * KD + k0;
    const float4 v0 = *(const float4*)(src);
    const float4 v1 = *(const float4*)(src + 4);
    int4 o;
    o.x = (int)pk2(v0.x, v0.y);
    o.y = (int)pk2(v0.z, v0.w);
    o.z = (int)pk2(v1.x, v1.y);
    o.w = (int)pk2(v1.z, v1.w);
    qb[u] = o;
  }
}

// ---------------- K1: 32x32 MFMA screen + fp64 refine ----------------
__global__ __launch_bounds__(512, 1) void wr_mfma(const float* __restrict__ qry,
                                                  const float* __restrict__ img,
                                                  const int4* __restrict__ qb,
                                                  const int4* __restrict__ ib,
                                                  int* __restrict__ out) {
  const int bid = (int)blockIdx.x;               // 0..255
  const int b = (bid & 7) >> 1;                  // batch pinned to XCD pair
  const int qt = ((bid >> 3) << 1) | (bid & 1);  // 0..63
  const int qbase = qt * 64;

  const int tid = (int)threadIdx.x;
  const int lane = tid & 63;
  const int w = tid >> 6;        // 0..7 -> m-eighth (32 tiles of 32 m)
  const int l31 = lane & 31;
  const int lh = lane >> 5;      // 0..1

  const int4* Qb = qb + (size_t)b * 65536 + qt * 1024;
  const int4* ibc = ib + (size_t)b * 131072 + w * 16384;

  // query fragments pinned: 2 q-halves x 8 k-slices. B[k=ks*16+lh*8+j][q=l31]
  bf16x8 bfrag[2][8];  // 64 VGPRs
#pragma unroll
  for (int h = 0; h < 2; ++h)
#pragma unroll
    for (int ks = 0; ks < 8; ++ks)
      bfrag[h][ks] = *(const bf16x8*)&Qb[h * 512 + ks * 64 + lane];

  float tch[2][4];  // one packed-key top-4 chain per q-half
#pragma unroll
  for (int c = 0; c < 2; ++c)
#pragma unroll
    for (int e = 0; e < 4; ++e) tch[c][e] = -FLT_MAX;

  bf16x8 A0[8], A1[8];  // 2-deep ring, 32 VGPRs each

  auto loadA = [&](bf16x8* A, int t) {
    const int4* p = ibc + t * 512 + lane;
#pragma unroll
    for (int ks = 0; ks < 8; ++ks) A[ks] = *(const bf16x8*)&p[ks * 64];
  };

  const f32x16 z16 = {0.f, 0.f, 0.f, 0.f, 0.f, 0.f, 0.f, 0.f,
                      0.f, 0.f, 0.f, 0.f, 0.f, 0.f, 0.f, 0.f};

  int hl = 2;
  int vbase = 2047 - 4 * lh;  // kr = vbase - row; m_local = tile*32+row+4*lh

  auto step = [&](bf16x8* A) {
    // all 16 MFMAs consume A before the refill below (ring-reuse hazard)
    f32x16 c0 = __builtin_amdgcn_mfma_f32_32x32x16_bf16(A[0], bfrag[0][0], z16,
                                                        0, 0, 0);
    f32x16 c1 = __builtin_amdgcn_mfma_f32_32x32x16_bf16(A[0], bfrag[1][0], z16,
                                                        0, 0, 0);
#pragma unroll
    for (int ks = 1; ks < 8; ++ks) {
      c0 = __builtin_amdgcn_mfma_f32_32x32x16_bf16(A[ks], bfrag[0][ks], c0,
                                                   0, 0, 0);
      c1 = __builtin_amdgcn_mfma_f32_32x32x16_bf16(A[ks], bfrag[1][ks], c1,
                                                   0, 0, 0);
    }
    if (hl < 32) loadA(A, hl);  // refill for use 2 steps later
    ++hl;
#pragma unroll
    for (int rg = 0; rg < 16; ++rg) {
      const unsigned kr = (unsigned)(vbase - ((rg & 3) + 8 * (rg >> 2)));
      float k = __uint_as_float((__float_as_uint(c0[rg]) & 0xFFFFF800u) | kr);
      tch[0][3] = fmed3(k, tch[0][2], tch[0][3]);
      tch[0][2] = fmed3(k, tch[0][1], tch[0][2]);
      tch[0][1] = fmed3(k, tch[0][0], tch[0][1]);
      tch[0][0] = fmaxf(tch[0][0], k);
      k = __uint_as_float((__float_as_uint(c1[rg]) & 0xFFFFF800u) | kr);
      tch[1][3] = fmed3(k, tch[1][2], tch[1][3]);
      tch[1][2] = fmed3(k, tch[1][1], tch[1][2]);
      tch[1][1] = fmed3(k, tch[1][0], tch[1][1]);
      tch[1][0] = fmaxf(tch[1][0], k);
    }
    vbase -= 32;
  };

  loadA(A0, 0);
  loadA(A1, 1);
  for (int g = 0; g < 16; ++g) { step(A0); step(A1); }  // tiles 0..31

  // ---- merge across lane-halves (rows complementary), snapshot-first ----
#pragma unroll
  for (int c = 0; c < 2; ++c) {
    float k4[4];
#pragma unroll
    for (int e = 0; e < 4; ++e) k4[e] = __shfl_xor(tch[c][e], 32, 64);
#pragma unroll
    for (int e = 0; e < 4; ++e) {
      const float k = k4[e];
      tch[c][3] = fmed3(k, tch[c][2], tch[c][3]);
      tch[c][2] = fmed3(k, tch[c][1], tch[c][2]);
      tch[c][1] = fmed3(k, tch[c][0], tch[c][1]);
      tch[c][0] = fmaxf(tch[c][0], k);
    }
  }

  // ---- 32 candidates per q-row (8 eighths x 4), 64 rows ----
  __shared__ float ck[64][33];
  __shared__ int top8[64][8];
  __shared__ double pd[64][8];
  __shared__ int pi[64][8];

  if (lane < 32) {
#pragma unroll
    for (int c = 0; c < 2; ++c)
#pragma unroll
      for (int e = 0; e < 4; ++e) ck[c * 32 + l31][w * 4 + e] = tch[c][e];
  }
  __syncthreads();

  // ---- rank-select top-8 of 32 packed keys per row (ranks unique) ----
  for (int p = tid; p < 2048; p += 512) {
    const int q = p >> 5;
    const int j = p & 31;
    const float k = ck[q][j];
    int rank = 0;
#pragma unroll 8
    for (int i = 0; i < 32; ++i) {
      const float o = ck[q][i];
      rank += (o > k) || (o == k && i < j);
    }
    if (rank < 8) {
      const unsigned bits = __float_as_uint(k);
      top8[q][rank] = (j >> 2) * 1024 + 2047 - (int)(bits & 0x7FFu);
    }
  }
  __syncthreads();

  // ---- fp64 refine: one candidate per thread (64 rows x 8) ----
  {
    const int q = tid >> 3;
    const int slot = tid & 7;
    const int m = top8[q][slot];
    const float* qrow = qry + ((size_t)b * NQ + qbase + q) * KD;
    const float* irow = img + ((size_t)b * NM + m) * KD;
    double s0 = 0.0, s1 = 0.0, s2 = 0.0, s3 = 0.0;
#pragma unroll
    for (int k = 0; k < KD; k += 4) {
      const float4 xv = *(const float4*)(qrow + k);
      const float4 yv = *(const float4*)(irow + k);
      s0 = fma((double)xv.x, (double)yv.x, s0);
      s1 = fma((double)xv.y, (double)yv.y, s1);
      s2 = fma((double)xv.z, (double)yv.z, s2);
      s3 = fma((double)xv.w, (double)yv.w, s3);
    }
    pd[q][slot] = (s0 + s1) + (s2 + s3);
    pi[q][slot] = m;
  }
  __syncthreads();

  // ---- exact top-4 of 8 refined, (value desc, index asc) ----
  if (tid < 64) {
    const int q = tid;
    double fv[4];
    int fi[4];
#pragma unroll
    for (int e = 0; e < 4; ++e) { fv[e] = -DBL_MAX; fi[e] = 0x7fffffff; }
    for (int sl = 0; sl < 8; ++sl) {
      const double v = pd[q][sl];
      const int m = pi[q][sl];
      const bool b0 = BETTER64(v, m, fv[0], fi[0]);
      const bool b1 = BETTER64(v, m, fv[1], fi[1]);
      const bool b2 = BETTER64(v, m, fv[2], fi[2]);
      const bool b3 = BETTER64(v, m, fv[3], fi[3]);
      fv[3] = b2 ? fv[2] : (b3 ? v : fv[3]);
      fi[3] = b2 ? fi[2] : (b3 ? m : fi[3]);
      fv[2] = b1 ? fv[1] : (b2 ? v : fv[2]);
      fi[2] = b1 ? fi[1] : (b2 ? m : fi[2]);
      fv[1] = b0 ? fv[0] : (b1 ? v : fv[1]);
      fi[1] = b0 ? fi[0] : (b1 ? m : fi[1]);
      fv[0] = b0 ? v : fv[0];
      fi[0] = b0 ? m : fi[0];
    }
    int4 o;
    o.x = fi[0]; o.y = fi[1]; o.z = fi[2]; o.w = fi[3];
    *(int4*)(out + ((size_t)b * NQ + qbase + q) * 4) = o;
  }
}

// ---------------- Fallback: fp32 LDS-tiled kernel (ws too small) ----------------
#define QT 64
#define MT 128
#define KC 64
#define NTHREADS 512

__global__ __launch_bounds__(NTHREADS) void wr_main(const float* __restrict__ qry,
                                                    const float* __restrict__ img,
                                                    int* __restrict__ out) {
  __shared__ __align__(16) float A_lds[KD * QT];
  __shared__ __align__(16) float B_lds[KC * MT];

  const int t = (int)threadIdx.x;
  const int b = (int)blockIdx.x >> 6;
  const int qbase = ((int)blockIdx.x & 63) * QT;

  const float* qp = qry + ((size_t)b * NQ + qbase) * KD;
  const float* ip = img + (size_t)b * NM * KD;

  {
    const int r = t >> 3;
    const int kc = t & 7;
    const float* src = qp + (size_t)r * KD;
#pragma unroll
    for (int i = 0; i < 4; ++i) {
      const int k0 = kc * 4 + i * 32;
      const float4 v = *(const float4*)(src + k0);
      A_lds[(k0 + 0) * QT + r] = v.x;
      A_lds[(k0 + 1) * QT + r] = v.y;
      A_lds[(k0 + 2) * QT + r] = v.z;
      A_lds[(k0 + 3) * QT + r] = v.w;
    }
  }

  const int qi = t >> 5;
  const int mi = t & 31;

  float tv[4][4];
  int ti[4][4];
#pragma unroll
  for (int j = 0; j < 4; ++j)
#pragma unroll
    for (int s = 0; s < 4; ++s) { tv[j][s] = -FLT_MAX; ti[j][s] = 0x7fffffff; }

  for (int tile = 0; tile < NM / MT; ++tile) {
    const int mbase = tile * MT;
    float acc[4][4];
#pragma unroll
    for (int j = 0; j < 4; ++j)
#pragma unroll
      for (int s = 0; s < 4; ++s) acc[j][s] = 0.0f;

    for (int kb = 0; kb < KD; kb += KC) {
      __syncthreads();
      {
        const int r = t >> 2;
        const int kc = t & 3;
        const float* src = ip + (size_t)(mbase + r) * KD + kb;
#pragma unroll
        for (int i = 0; i < 4; ++i) {
          const int k0 = kc * 4 + i * 16;
          const float4 v = *(const float4*)(src + k0);
          B_lds[(k0 + 0) * MT + r] = v.x;
          B_lds[(k0 + 1) * MT + r] = v.y;
          B_lds[(k0 + 2) * MT + r] = v.z;
          B_lds[(k0 + 3) * MT + r] = v.w;
        }
      }
      __syncthreads();

#pragma unroll 8
      for (int k = 0; k < KC; ++k) {
        const float4 av = *(const float4*)&A_lds[(kb + k) * QT + qi * 4];
        const float4 bv = *(const float4*)&B_lds[k * MT + mi * 4];
        acc[0][0] = fmaf(av.x, bv.x, acc[0][0]);
        acc[0][1] = fmaf(av.x, bv.y, acc[0][1]);
        acc[0][2] = fmaf(av.x, bv.z, acc[0][2]);
        acc[0][3] = fmaf(av.x, bv.w, acc[0][3]);
        acc[1][0] = fmaf(av.y, bv.x, acc[1][0]);
        acc[1][1] = fmaf(av.y, bv.y, acc[1][1]);
        acc[1][2] = fmaf(av.y, bv.z, acc[1][2]);
        acc[1][3] = fmaf(av.y, bv.w, acc[1][3]);
        acc[2][0] = fmaf(av.z, bv.x, acc[2][0]);
        acc[2][1] = fmaf(av.z, bv.y, acc[2][1]);
        acc[2][2] = fmaf(av.z, bv.z, acc[2][2]);
        acc[2][3] = fmaf(av.z, bv.w, acc[2][3]);
        acc[3][0] = fmaf(av.w, bv.x, acc[3][0]);
        acc[3][1] = fmaf(av.w, bv.y, acc[3][1]);
        acc[3][2] = fmaf(av.w, bv.z, acc[3][2]);
        acc[3][3] = fmaf(av.w, bv.w, acc[3][3]);
      }
    }

#pragma unroll
    for (int j = 0; j < 4; ++j) {
#pragma unroll
      for (int s = 0; s < 4; ++s) {
        const float v = acc[j][s];
        const int m = mbase + mi * 4 + s;
        const bool b0 = v > tv[j][0];
        const bool b1 = v > tv[j][1];
        const bool b2 = v > tv[j][2];
        const bool b3 = v > tv[j][3];
        tv[j][3] = b2 ? tv[j][2] : (b3 ? v : tv[j][3]);
        ti[j][3] = b2 ? ti[j][2] : (b3 ? m : ti[j][3]);
        tv[j][2] = b1 ? tv[j][1] : (b2 ? v : tv[j][2]);
        ti[j][2] = b1 ? ti[j][1] : (b2 ? m : ti[j][2]);
        tv[j][1] = b0 ? tv[j][0] : (b1 ? v : tv[j][1]);
        ti[j][1] = b0 ? ti[j][0] : (b1 ? m : ti[j][1]);
        tv[j][0] = b0 ? v : tv[j][0];
        ti[j][0] = b0 ? m : ti[j][0];
      }
    }
  }

  __syncthreads();
  int* idx_lds = (int*)B_lds;
#pragma unroll
  for (int j = 0; j < 4; ++j)
#pragma unroll
    for (int s = 0; s < 4; ++s)
      idx_lds[(qi * 4 + j) * 128 + mi * 4 + s] = ti[j][s];
  __syncthreads();

  double* pv = (double*)A_lds;
  int* piL = (int*)(A_lds + 4096);
  {
    const int r = t >> 3;
    const int slot = t & 7;
    const float* qrow = qp + (size_t)r * KD;
    double bv[4];
    int bi[4];
#pragma unroll
    for (int e = 0; e < 4; ++e) { bv[e] = -DBL_MAX; bi[e] = 0x7fffffff; }

    for (int c = 0; c < 16; ++c) {
      const int m = idx_lds[r * 128 + slot * 16 + c];
      const float* irow = ip + (size_t)m * KD;
      double s0 = 0.0, s1 = 0.0, s2 = 0.0, s3 = 0.0;
#pragma unroll
      for (int k = 0; k < KD; k += 4) {
        const float4 xv = *(const float4*)(qrow + k);
        const float4 yv = *(const float4*)(irow + k);
        s0 = fma((double)xv.x, (double)yv.x, s0);
        s1 = fma((double)xv.y, (double)yv.y, s1);
        s2 = fma((double)xv.z, (double)yv.z, s2);
        s3 = fma((double)xv.w, (double)yv.w, s3);
      }
      const double v = (s0 + s1) + (s2 + s3);
      const bool b0 = BETTER64(v, m, bv[0], bi[0]);
      const bool b1 = BETTER64(v, m, bv[1], bi[1]);
      const bool b2 = BETTER64(v, m, bv[2], bi[2]);
      const bool b3 = BETTER64(v, m, bv[3], bi[3]);
      bv[3] = b2 ? bv[2] : (b3 ? v : bv[3]);
      bi[3] = b2 ? bi[2] : (b3 ? m : bi[3]);
      bv[2] = b1 ? bv[1] : (b2 ? v : bv[2]);
      bi[2] = b1 ? bi[1] : (b2 ? m : bi[2]);
      bv[1] = b0 ? bv[0] : (b1 ? v : bv[1]);
      bi[1] = b0 ? bi[0] : (b1 ? m : bi[1]);
      bv[0] = b0 ? v : bv[0];
      bi[0] = b0 ? m : bi[0];
    }
#pragma unroll
    for (int e = 0; e < 4; ++e) {
      pv[t * 4 + e] = bv[e];
      piL[t * 4 + e] = bi[e];
    }
  }
  __syncthreads();

  if (t < QT) {
    double fv[4];
    int fi[4];
#pragma unroll
    for (int e = 0; e < 4; ++e) { fv[e] = -DBL_MAX; fi[e] = 0x7fffffff; }
    for (int sl = 0; sl < 8; ++sl) {
#pragma unroll
      for (int e = 0; e < 4; ++e) {
        const double v = pv[(t * 8 + sl) * 4 + e];
        const int m = piL[(t * 8 + sl) * 4 + e];
        const bool b0 = BETTER64(v, m, fv[0], fi[0]);
        const bool b1 = BETTER64(v, m, fv[1], fi[1]);
        const bool b2 = BETTER64(v, m, fv[2], fi[2]);
        const bool b3 = BETTER64(v, m, fv[3], fi[3]);
        fv[3] = b2 ? fv[2] : (b3 ? v : fv[3]);
        fi[3] = b2 ? fi[2] : (b3 ? m : fi[3]);
        fv[2] = b1 ? fv[1] : (b2 ? v : fv[2]);
        fi[2] = b1 ? fi[1] : (b2 ? m : fi[2]);
        fv[1] = b0 ? fv[0] : (b1 ? v : fv[1]);
        fi[1] = b0 ? fi[0] : (b1 ? m : fi[1]);
        fv[0] = b0 ? v : fv[0];
        fi[0] = b0 ? m : fi[0];
      }
    }
    int4 o;
    o.x = fi[0]; o.y = fi[1]; o.z = fi[2]; o.w = fi[3];
    *(int4*)(out + ((size_t)b * NQ + qbase + t) * 4) = o;
  }
}

extern "C" void kernel_launch(void* const* d_in, const int* in_sizes, int n_in,
                              void* d_out, int out_size, void* d_ws, size_t ws_size,
                              hipStream_t stream) {
  const float* qry = (const float*)d_in[0];  // (4, 4096, 128) fp32
  const float* img = (const float*)d_in[1];  // (4, 8192, 128) fp32
  int* out = (int*)d_out;                    // (4, 4096, 4) int32

  const size_t qbBytes = (size_t)NBATCH * NQ * KD * sizeof(ushort_t);  // 4 MB
  const size_t ibBytes = (size_t)NBATCH * NM * KD * sizeof(ushort_t);  // 8 MB

  if (ws_size >= qbBytes + ibBytes) {
    int4* qb = (int4*)d_ws;
    int4* ib = (int4*)((char*)d_ws + qbBytes);
    wr_cvt<<<3072, 256, 0, stream>>>(qry, img, qb, ib);
    wr_mfma<<<256, 512, 0, stream>>>(qry, img, qb, ib, out);
  } else {
    wr_main<<<NBATCH * (NQ / QT), NTHREADS, 0, stream>>>(qry, img, out);
  }
}